// Round 1
// baseline (329.286 us; speedup 1.0000x reference)
//
#include <hip/hip_runtime.h>
#include <math.h>

#define HI 128
#define WI 128
#define BB 2
#define PG 1024

#define OFF_ALPHA (BB*3*HI*WI)            /* 98304  */
#define OFF_ESTC  (OFF_ALPHA + BB*HI*WI)  /* 131072 */
#define OFF_ESTW  (OFF_ESTC + BB*PG*3)    /* 137216 */
#define OFF_RADII (OFF_ESTW + BB*PG)      /* 139264 */

// ws layout: pre[B*P*12] floats, then srt[B*P*12] floats.
// record: [0]px [1]py [2]A [3]B [4]C [5]pmin [6]op [7]cR [8]cG [9]cB [10]depth/idx [11]pad

__global__ __launch_bounds__(256) void preprocess_kernel(
    const float* __restrict__ means, const float* __restrict__ sh,
    const float* __restrict__ opac, const float* __restrict__ scales,
    const float* __restrict__ rots, const float* __restrict__ vm,
    const float* __restrict__ pm, const float* __restrict__ campos,
    float* __restrict__ pre, float* __restrict__ radii_out)
{
  int gid = blockIdx.x * blockDim.x + threadIdx.x;
  if (gid >= BB * PG) return;

  float mx = means[gid*3+0], my = means[gid*3+1], mz = means[gid*3+2];

  // hom = proj * [m,1]; p_proj = hom.xyz / (hom.w + 1e-7)
  float hom0 = pm[0]*mx + pm[1]*my + pm[2]*mz + pm[3];
  float hom1 = pm[4]*mx + pm[5]*my + pm[6]*mz + pm[7];
  float hom3 = pm[12]*mx + pm[13]*my + pm[14]*mz + pm[15];
  float p_w  = 1.0f / (hom3 + 1e-7f);
  float pp0 = hom0 * p_w, pp1 = hom1 * p_w;

  float pv0   = vm[0]*mx + vm[1]*my + vm[2]*mz  + vm[3];
  float pv1   = vm[4]*mx + vm[5]*my + vm[6]*mz  + vm[7];
  float depth = vm[8]*mx + vm[9]*my + vm[10]*mz + vm[11];

  // quaternion -> R
  float qr = rots[gid*4+0], qx = rots[gid*4+1], qy = rots[gid*4+2], qz = rots[gid*4+3];
  float qn = sqrtf(qr*qr + qx*qx + qy*qy + qz*qz);
  qr /= qn; qx /= qn; qy /= qn; qz /= qn;
  float R00 = 1.0f-2.0f*(qy*qy+qz*qz), R01 = 2.0f*(qx*qy-qr*qz), R02 = 2.0f*(qx*qz+qr*qy);
  float R10 = 2.0f*(qx*qy+qr*qz), R11 = 1.0f-2.0f*(qx*qx+qz*qz), R12 = 2.0f*(qy*qz-qr*qx);
  float R20 = 2.0f*(qx*qz-qr*qy), R21 = 2.0f*(qy*qz+qr*qx), R22 = 1.0f-2.0f*(qx*qx+qy*qy);

  float s0 = scales[gid*3+0], s1 = scales[gid*3+1], s2 = scales[gid*3+2];
  float M00=R00*s0, M01=R01*s1, M02=R02*s2;
  float M10=R10*s0, M11=R11*s1, M12=R12*s2;
  float M20=R20*s0, M21=R21*s1, M22=R22*s2;
  float S00 = M00*M00+M01*M01+M02*M02;
  float S01 = M00*M10+M01*M11+M02*M12;
  float S02 = M00*M20+M01*M21+M02*M22;
  float S11 = M10*M10+M11*M11+M12*M12;
  float S12 = M10*M20+M11*M21+M12*M22;
  float S22 = M20*M20+M21*M21+M22*M22;

  const float fx = 128.0f, fyc = 128.0f;  // W/(2 tanfovx), H/(2 tanfovy)
  float tz = depth;
  float txc = fminf(fmaxf(pv0/tz, -0.65f), 0.65f) * tz;
  float tyc = fminf(fmaxf(pv1/tz, -0.65f), 0.65f) * tz;
  float J00 = fx/tz,  J02 = -fx*txc/(tz*tz);
  float J11 = fyc/tz, J12 = -fyc*tyc/(tz*tz);

  // T = J * view[:3,:3]
  float T00 = J00*vm[0] + J02*vm[8];
  float T01 = J00*vm[1] + J02*vm[9];
  float T02 = J00*vm[2] + J02*vm[10];
  float T10 = J11*vm[4] + J12*vm[8];
  float T11 = J11*vm[5] + J12*vm[9];
  float T12 = J11*vm[6] + J12*vm[10];

  float TS00 = T00*S00 + T01*S01 + T02*S02;
  float TS01 = T00*S01 + T01*S11 + T02*S12;
  float TS02 = T00*S02 + T01*S12 + T02*S22;
  float TS10 = T10*S00 + T11*S01 + T12*S02;
  float TS11 = T10*S01 + T11*S11 + T12*S12;
  float TS12 = T10*S02 + T11*S12 + T12*S22;

  float c00 = TS00*T00 + TS01*T01 + TS02*T02 + 0.3f;
  float c01 = TS00*T10 + TS01*T11 + TS02*T12;
  float c11 = TS10*T10 + TS11*T11 + TS12*T12 + 0.3f;

  float det = c00*c11 - c01*c01;
  bool valid = (depth > 0.2f) && (det > 1e-12f);
  float inv_det = 1.0f / (det > 1e-12f ? det : 1.0f);
  float A  =  c11 * inv_det;
  float Bc = -c01 * inv_det;
  float Cc =  c00 * inv_det;
  float mid = 0.5f * (c00 + c11);
  float lam = mid + sqrtf(fmaxf(mid*mid - det, 0.1f));
  float radii = valid ? ceilf(3.0f * sqrtf(lam)) : 0.0f;

  float px = ((pp0 + 1.0f)*WI - 1.0f)*0.5f;
  float py = ((pp1 + 1.0f)*HI - 1.0f)*0.5f;

  // SH degree 3
  float dxr = mx - campos[0], dyr = my - campos[1], dzr = mz - campos[2];
  float dn = sqrtf(dxr*dxr + dyr*dyr + dzr*dzr);
  float x = dxr/dn, y = dyr/dn, z = dzr/dn;
  float xx=x*x, yy=y*y, zz=z*z, xy=x*y, yz=y*z, xz=x*z;
  const float* S = sh + gid*48;
  float col[3];
  #pragma unroll
  for (int c = 0; c < 3; ++c) {
    float r = 0.28209479177387814f * S[0+c];
    r -= 0.4886025119029199f * y * S[3+c];
    r += 0.4886025119029199f * z * S[6+c];
    r -= 0.4886025119029199f * x * S[9+c];
    r += 1.0925484305920792f  * xy * S[12+c];
    r += -1.0925484305920792f * yz * S[15+c];
    r += 0.31539156525252005f * (2.0f*zz-xx-yy) * S[18+c];
    r += -1.0925484305920792f * xz * S[21+c];
    r += 0.5462742152960396f  * (xx-yy) * S[24+c];
    r += -0.5900435899266435f * y * (3.0f*xx-yy) * S[27+c];
    r += 2.890611442640554f   * xy * z * S[30+c];
    r += -0.4570457994644658f * y * (4.0f*zz-xx-yy) * S[33+c];
    r += 0.3731763325901154f  * z * (2.0f*zz-3.0f*xx-3.0f*yy) * S[36+c];
    r += -0.4570457994644658f * x * (4.0f*zz-xx-yy) * S[39+c];
    r += 1.445305721320277f   * z * (xx-yy) * S[42+c];
    r += -0.5900435899266435f * x * (xx-3.0f*yy) * S[45+c];
    col[c] = fmaxf(r + 0.5f, 0.0f);
  }

  float op = opac[gid];
  float pmin = valid ? -logf(255.0f * op) : 1e30f;

  float* dst = pre + gid*12;
  dst[0]=px; dst[1]=py; dst[2]=A; dst[3]=Bc; dst[4]=Cc; dst[5]=pmin; dst[6]=op;
  dst[7]=col[0]; dst[8]=col[1]; dst[9]=col[2]; dst[10]=depth; dst[11]=0.0f;
  radii_out[gid] = radii;
}

// One block per batch: stable (depth, idx) bitonic sort, then gather records.
__global__ __launch_bounds__(1024) void sort_pack_kernel(
    const float* __restrict__ pre, float* __restrict__ srt)
{
  __shared__ float sk[PG];
  __shared__ int   si[PG];
  int b = blockIdx.x, t = threadIdx.x;
  sk[t] = pre[(b*PG + t)*12 + 10];
  si[t] = t;
  __syncthreads();
  for (int k = 2; k <= PG; k <<= 1) {
    for (int j = k >> 1; j > 0; j >>= 1) {
      int ixj = t ^ j;
      if (ixj > t) {
        float d0 = sk[t], d1 = sk[ixj];
        int   i0 = si[t], i1 = si[ixj];
        bool gt = (d0 > d1) || (d0 == d1 && i0 > i1);
        bool up = ((t & k) == 0);
        if (gt == up) { sk[t]=d1; sk[ixj]=d0; si[t]=i1; si[ixj]=i0; }
      }
      __syncthreads();
    }
  }
  int g = si[t];
  const float* src = pre + (b*PG + g)*12;
  float* dst = srt + (b*PG + t)*12;
  #pragma unroll
  for (int q = 0; q < 10; ++q) dst[q] = src[q];
  ((int*)dst)[10] = g;   // original index as int bits
  dst[11] = 0.0f;
}

__global__ __launch_bounds__(64) void render_kernel(
    const float* __restrict__ srt, const float* __restrict__ target,
    const float* __restrict__ bg, float* __restrict__ out)
{
  const int b = blockIdx.z;
  const int x = blockIdx.x*8 + threadIdx.x;
  const int y = blockIdx.y*8 + threadIdx.y;
  const float fx = (float)x, fy = (float)y;

  const float t0 = target[((b*3+0)*HI + y)*WI + x];
  const float t1 = target[((b*3+1)*HI + y)*WI + x];
  const float t2 = target[((b*3+2)*HI + y)*WI + x];

  float* est_col = out + OFF_ESTC + b*PG*3;
  float* est_w   = out + OFF_ESTW + b*PG;
  const float4* gsrc = (const float4*)(srt + (size_t)b*PG*12);

  float T = 1.0f, a0 = 0.0f, a1 = 0.0f, a2 = 0.0f;

  for (int g = 0; g < PG; ++g) {
    float4 q0 = gsrc[g*3+0];   // px,py,A,B
    float4 q1 = gsrc[g*3+1];   // C,pmin,op,cR
    float dx = q0.x - fx, dy = q0.y - fy;
    float power = -0.5f*(q0.z*dx*dx + q1.x*dy*dy) - q0.w*dx*dy;
    if (!(power <= 0.0f && power >= q1.y)) continue;   // NaN-safe skip
    float alpha = fminf(0.99f, q1.z * __expf(power));
    if (alpha < (1.0f/255.0f)) continue;
    float4 q2 = gsrc[g*3+2];   // cG,cB,origIdxBits,pad
    float w = alpha * T;
    a0 += w * q1.w; a1 += w * q2.x; a2 += w * q2.y;
    T *= (1.0f - alpha);
    int orig = __float_as_int(q2.z);
    atomicAdd(&est_col[orig*3+0], w * t0);
    atomicAdd(&est_col[orig*3+1], w * t1);
    atomicAdd(&est_col[orig*3+2], w * t2);
    atomicAdd(&est_w[orig], w);
    if (T < 1e-5f) break;
  }

  out[((b*3+0)*HI + y)*WI + x] = a0 + T * bg[b*3+0];
  out[((b*3+1)*HI + y)*WI + x] = a1 + T * bg[b*3+1];
  out[((b*3+2)*HI + y)*WI + x] = a2 + T * bg[b*3+2];
  out[OFF_ALPHA + (b*HI + y)*WI + x] = 1.0f - T;
}

extern "C" void kernel_launch(void* const* d_in, const int* in_sizes, int n_in,
                              void* d_out, int out_size, void* d_ws, size_t ws_size,
                              hipStream_t stream) {
  const float* means  = (const float*)d_in[0];
  const float* sh     = (const float*)d_in[1];
  const float* opac   = (const float*)d_in[2];
  const float* scales = (const float*)d_in[3];
  const float* rots   = (const float*)d_in[4];
  const float* target = (const float*)d_in[5];
  const float* bg     = (const float*)d_in[6];
  const float* vm     = (const float*)d_in[7];
  const float* pm     = (const float*)d_in[8];
  const float* campos = (const float*)d_in[9];
  float* out = (float*)d_out;

  float* pre = (float*)d_ws;
  float* srt = pre + BB*PG*12;

  // zero est_color + est_weight (accumulated via atomics)
  hipMemsetAsync(out + OFF_ESTC, 0, (size_t)(BB*PG*4) * sizeof(float), stream);

  preprocess_kernel<<<(BB*PG + 255)/256, 256, 0, stream>>>(
      means, sh, opac, scales, rots, vm, pm, campos, pre, out + OFF_RADII);

  sort_pack_kernel<<<BB, PG, 0, stream>>>(pre, srt);

  dim3 grid(WI/8, HI/8, BB), block(8, 8);
  render_kernel<<<grid, block, 0, stream>>>(srt, target, bg, out);
}

// Round 2
// 58.569 us; speedup vs baseline: 5.6221x; 5.6221x over previous
//
#include <hip/hip_runtime.h>
#include <math.h>

#define HI 128
#define WI 128
#define BB 2
#define PG 1024

#define OFF_ALPHA (BB*3*HI*WI)            /* 98304  */
#define OFF_ESTC  (OFF_ALPHA + BB*HI*WI)  /* 131072 */
#define OFF_ESTW  (OFF_ESTC + BB*PG*3)    /* 137216 */
#define OFF_RADII (OFF_ESTW + BB*PG)      /* 139264 */

// ws layout:
//   pre  [B*P*16] floats : [0]px [1]py [2]A [3]B [4]C [5]pmin [6]op [7]depth
//                          [8]cR [9]cG [10]cB [11]ex [12]ey [13..15] unused
//   srt  [B*P*12] floats : q0(px,py,A,B) q1(C,pmin,op,idxbits) q2(cR,cG,cB,pad)
//   cull [B*P] float4    : (px,py,ex,ey)

__global__ __launch_bounds__(256) void preprocess_kernel(
    const float* __restrict__ means, const float* __restrict__ sh,
    const float* __restrict__ opac, const float* __restrict__ scales,
    const float* __restrict__ rots, const float* __restrict__ vm,
    const float* __restrict__ pm, const float* __restrict__ campos,
    float* __restrict__ pre, float* __restrict__ radii_out)
{
  int gid = blockIdx.x * blockDim.x + threadIdx.x;
  if (gid >= BB * PG) return;

  float mx = means[gid*3+0], my = means[gid*3+1], mz = means[gid*3+2];

  float hom0 = pm[0]*mx + pm[1]*my + pm[2]*mz + pm[3];
  float hom1 = pm[4]*mx + pm[5]*my + pm[6]*mz + pm[7];
  float hom3 = pm[12]*mx + pm[13]*my + pm[14]*mz + pm[15];
  float p_w  = 1.0f / (hom3 + 1e-7f);
  float pp0 = hom0 * p_w, pp1 = hom1 * p_w;

  float pv0   = vm[0]*mx + vm[1]*my + vm[2]*mz  + vm[3];
  float pv1   = vm[4]*mx + vm[5]*my + vm[6]*mz  + vm[7];
  float depth = vm[8]*mx + vm[9]*my + vm[10]*mz + vm[11];

  float qr = rots[gid*4+0], qx = rots[gid*4+1], qy = rots[gid*4+2], qz = rots[gid*4+3];
  float qn = sqrtf(qr*qr + qx*qx + qy*qy + qz*qz);
  qr /= qn; qx /= qn; qy /= qn; qz /= qn;
  float R00 = 1.0f-2.0f*(qy*qy+qz*qz), R01 = 2.0f*(qx*qy-qr*qz), R02 = 2.0f*(qx*qz+qr*qy);
  float R10 = 2.0f*(qx*qy+qr*qz), R11 = 1.0f-2.0f*(qx*qx+qz*qz), R12 = 2.0f*(qy*qz-qr*qx);
  float R20 = 2.0f*(qx*qz-qr*qy), R21 = 2.0f*(qy*qz+qr*qx), R22 = 1.0f-2.0f*(qx*qx+qy*qy);

  float s0 = scales[gid*3+0], s1 = scales[gid*3+1], s2 = scales[gid*3+2];
  float M00=R00*s0, M01=R01*s1, M02=R02*s2;
  float M10=R10*s0, M11=R11*s1, M12=R12*s2;
  float M20=R20*s0, M21=R21*s1, M22=R22*s2;
  float S00 = M00*M00+M01*M01+M02*M02;
  float S01 = M00*M10+M01*M11+M02*M12;
  float S02 = M00*M20+M01*M21+M02*M22;
  float S11 = M10*M10+M11*M11+M12*M12;
  float S12 = M10*M20+M11*M21+M12*M22;
  float S22 = M20*M20+M21*M21+M22*M22;

  const float fx = 128.0f, fyc = 128.0f;
  float tz = depth;
  float txc = fminf(fmaxf(pv0/tz, -0.65f), 0.65f) * tz;
  float tyc = fminf(fmaxf(pv1/tz, -0.65f), 0.65f) * tz;
  float J00 = fx/tz,  J02 = -fx*txc/(tz*tz);
  float J11 = fyc/tz, J12 = -fyc*tyc/(tz*tz);

  float T00 = J00*vm[0] + J02*vm[8];
  float T01 = J00*vm[1] + J02*vm[9];
  float T02 = J00*vm[2] + J02*vm[10];
  float T10 = J11*vm[4] + J12*vm[8];
  float T11 = J11*vm[5] + J12*vm[9];
  float T12 = J11*vm[6] + J12*vm[10];

  float TS00 = T00*S00 + T01*S01 + T02*S02;
  float TS01 = T00*S01 + T01*S11 + T02*S12;
  float TS02 = T00*S02 + T01*S12 + T02*S22;
  float TS10 = T10*S00 + T11*S01 + T12*S02;
  float TS11 = T10*S01 + T11*S11 + T12*S12;
  float TS12 = T10*S02 + T11*S12 + T12*S22;

  float c00 = TS00*T00 + TS01*T01 + TS02*T02 + 0.3f;
  float c01 = TS00*T10 + TS01*T11 + TS02*T12;
  float c11 = TS10*T10 + TS11*T11 + TS12*T12 + 0.3f;

  float det = c00*c11 - c01*c01;
  bool valid = (depth > 0.2f) && (det > 1e-12f);
  float inv_det = 1.0f / (det > 1e-12f ? det : 1.0f);
  float A  =  c11 * inv_det;
  float Bc = -c01 * inv_det;
  float Cc =  c00 * inv_det;
  float mid = 0.5f * (c00 + c11);
  float lam = mid + sqrtf(fmaxf(mid*mid - det, 0.1f));
  float radii = valid ? ceilf(3.0f * sqrtf(lam)) : 0.0f;

  float px = ((pp0 + 1.0f)*WI - 1.0f)*0.5f;
  float py = ((pp1 + 1.0f)*HI - 1.0f)*0.5f;

  // SH degree 3
  float dxr = mx - campos[0], dyr = my - campos[1], dzr = mz - campos[2];
  float dn = sqrtf(dxr*dxr + dyr*dyr + dzr*dzr);
  float x = dxr/dn, y = dyr/dn, z = dzr/dn;
  float xx=x*x, yy=y*y, zz=z*z, xy=x*y, yz=y*z, xz=x*z;
  const float* S = sh + gid*48;
  float col[3];
  #pragma unroll
  for (int c = 0; c < 3; ++c) {
    float r = 0.28209479177387814f * S[0+c];
    r -= 0.4886025119029199f * y * S[3+c];
    r += 0.4886025119029199f * z * S[6+c];
    r -= 0.4886025119029199f * x * S[9+c];
    r += 1.0925484305920792f  * xy * S[12+c];
    r += -1.0925484305920792f * yz * S[15+c];
    r += 0.31539156525252005f * (2.0f*zz-xx-yy) * S[18+c];
    r += -1.0925484305920792f * xz * S[21+c];
    r += 0.5462742152960396f  * (xx-yy) * S[24+c];
    r += -0.5900435899266435f * y * (3.0f*xx-yy) * S[27+c];
    r += 2.890611442640554f   * xy * z * S[30+c];
    r += -0.4570457994644658f * y * (4.0f*zz-xx-yy) * S[33+c];
    r += 0.3731763325901154f  * z * (2.0f*zz-3.0f*xx-3.0f*yy) * S[36+c];
    r += -0.4570457994644658f * x * (4.0f*zz-xx-yy) * S[39+c];
    r += 1.445305721320277f   * z * (xx-yy) * S[42+c];
    r += -0.5900435899266435f * x * (xx-3.0f*yy) * S[45+c];
    col[c] = fmaxf(r + 0.5f, 0.0f);
  }

  float op = opac[gid];
  float tau = logf(255.0f * op);           // -pmin
  bool rok = valid && (tau > 0.0f);
  float ex = rok ? sqrtf(2.0f*tau*c00) + 0.02f : -1e9f;
  float ey = rok ? sqrtf(2.0f*tau*c11) + 0.02f : -1e9f;

  float* dst = pre + gid*16;
  dst[0]=px; dst[1]=py; dst[2]=A; dst[3]=Bc; dst[4]=Cc; dst[5]=-tau; dst[6]=op;
  dst[7]=depth; dst[8]=col[0]; dst[9]=col[1]; dst[10]=col[2];
  dst[11]=ex; dst[12]=ey; dst[13]=0.0f; dst[14]=0.0f; dst[15]=0.0f;
  radii_out[gid] = radii;
}

// One block per batch: stable (depth, idx) bitonic sort, then gather records.
__global__ __launch_bounds__(1024) void sort_pack_kernel(
    const float* __restrict__ pre, float* __restrict__ srt,
    float4* __restrict__ cull)
{
  __shared__ float sk[PG];
  __shared__ int   si[PG];
  int b = blockIdx.x, t = threadIdx.x;
  sk[t] = pre[(b*PG + t)*16 + 7];
  si[t] = t;
  __syncthreads();
  for (int k = 2; k <= PG; k <<= 1) {
    for (int j = k >> 1; j > 0; j >>= 1) {
      int ixj = t ^ j;
      if (ixj > t) {
        float d0 = sk[t], d1 = sk[ixj];
        int   i0 = si[t], i1 = si[ixj];
        bool gt = (d0 > d1) || (d0 == d1 && i0 > i1);
        bool up = ((t & k) == 0);
        if (gt == up) { sk[t]=d1; sk[ixj]=d0; si[t]=i1; si[ixj]=i0; }
      }
      __syncthreads();
    }
  }
  int g = si[t];
  const float* src = pre + (b*PG + g)*16;
  float* dst = srt + (b*PG + t)*12;
  dst[0]=src[0]; dst[1]=src[1]; dst[2]=src[2]; dst[3]=src[3];
  dst[4]=src[4]; dst[5]=src[5]; dst[6]=src[6]; ((int*)dst)[7]=g;
  dst[8]=src[8]; dst[9]=src[9]; dst[10]=src[10]; dst[11]=0.0f;
  cull[b*PG + t] = make_float4(src[0], src[1], src[11], src[12]);
}

__global__ __launch_bounds__(64) void render_kernel(
    const float* __restrict__ srt, const float4* __restrict__ cull,
    const float* __restrict__ target, const float* __restrict__ bg,
    float* __restrict__ out)
{
  const int b = blockIdx.z;
  const int t = threadIdx.x;
  const int x = blockIdx.x*8 + (t & 7);
  const int y = blockIdx.y*8 + (t >> 3);
  const float fxp = (float)x, fyp = (float)y;
  const float tx0 = (float)(blockIdx.x*8), ty0 = (float)(blockIdx.y*8);

  __shared__ int sidx[PG];

  // ---- build per-tile survivor list (order-preserving) ----
  const float4* csrc = cull + b*PG;
  int total = 0;
  #pragma unroll
  for (int c0 = 0; c0 < PG; c0 += 64) {
    float4 cv = csrc[c0 + t];
    bool ok = (cv.x + cv.z >= tx0) && (cv.x - cv.z <= tx0 + 7.0f)
           && (cv.y + cv.w >= ty0) && (cv.y - cv.w <= ty0 + 7.0f);
    unsigned long long m = __ballot(ok);
    if (ok) {
      int pos = total + __popcll(m & ((1ull << t) - 1ull));
      sidx[pos] = c0 + t;
    }
    total += __popcll(m);
  }
  __syncthreads();

  const float t0 = target[((b*3+0)*HI + y)*WI + x];
  const float t1 = target[((b*3+1)*HI + y)*WI + x];
  const float t2 = target[((b*3+2)*HI + y)*WI + x];

  float* est_col = out + OFF_ESTC + b*PG*3;
  float* est_w   = out + OFF_ESTW + b*PG;
  const float4* gsrc = (const float4*)(srt + (size_t)b*PG*12);

  float T = 1.0f, a0 = 0.0f, a1 = 0.0f, a2 = 0.0f;

  for (int i = 0; i < total; ++i) {
    int g = sidx[i];
    float4 q0 = gsrc[g*3+0];   // px,py,A,B
    float4 q1 = gsrc[g*3+1];   // C,pmin,op,idxbits
    float4 q2 = gsrc[g*3+2];   // cR,cG,cB,pad
    float dx = q0.x - fxp, dy = q0.y - fyp;
    float power = -0.5f*(q0.z*dx*dx + q1.x*dy*dy) - q0.w*dx*dy;
    float alpha = fminf(0.99f, q1.z * __expf(power));
    bool keep = (power <= 0.0f) && (alpha >= (1.0f/255.0f));
    float w = keep ? alpha * T : 0.0f;
    a0 += w * q2.x; a1 += w * q2.y; a2 += w * q2.z;
    T -= w;                     // == T*(1-alpha) when keep

    if (__any(w > 0.0f)) {
      float rw = w, r0 = w*t0, r1 = w*t1, r2 = w*t2;
      #pragma unroll
      for (int o = 32; o; o >>= 1) {
        rw += __shfl_xor(rw, o);
        r0 += __shfl_xor(r0, o);
        r1 += __shfl_xor(r1, o);
        r2 += __shfl_xor(r2, o);
      }
      if (t == 0) {
        int orig = __float_as_int(q1.w);
        atomicAdd(&est_col[orig*3+0], r0);
        atomicAdd(&est_col[orig*3+1], r1);
        atomicAdd(&est_col[orig*3+2], r2);
        atomicAdd(&est_w[orig], rw);
      }
    }
  }

  out[((b*3+0)*HI + y)*WI + x] = a0 + T * bg[b*3+0];
  out[((b*3+1)*HI + y)*WI + x] = a1 + T * bg[b*3+1];
  out[((b*3+2)*HI + y)*WI + x] = a2 + T * bg[b*3+2];
  out[OFF_ALPHA + (b*HI + y)*WI + x] = 1.0f - T;
}

extern "C" void kernel_launch(void* const* d_in, const int* in_sizes, int n_in,
                              void* d_out, int out_size, void* d_ws, size_t ws_size,
                              hipStream_t stream) {
  const float* means  = (const float*)d_in[0];
  const float* sh     = (const float*)d_in[1];
  const float* opac   = (const float*)d_in[2];
  const float* scales = (const float*)d_in[3];
  const float* rots   = (const float*)d_in[4];
  const float* target = (const float*)d_in[5];
  const float* bg     = (const float*)d_in[6];
  const float* vm     = (const float*)d_in[7];
  const float* pm     = (const float*)d_in[8];
  const float* campos = (const float*)d_in[9];
  float* out = (float*)d_out;

  float* pre  = (float*)d_ws;                 // 2048*16 floats
  float* srt  = pre + BB*PG*16;               // 2048*12 floats
  float4* cul = (float4*)(srt + BB*PG*12);    // 2048 float4

  hipMemsetAsync(out + OFF_ESTC, 0, (size_t)(BB*PG*4) * sizeof(float), stream);

  preprocess_kernel<<<(BB*PG + 255)/256, 256, 0, stream>>>(
      means, sh, opac, scales, rots, vm, pm, campos, pre, out + OFF_RADII);

  sort_pack_kernel<<<BB, PG, 0, stream>>>(pre, srt, cul);

  dim3 grid(WI/8, HI/8, BB), block(64, 1);
  render_kernel<<<grid, block, 0, stream>>>(srt, cul, target, bg, out);
}

// Round 3
// 45.969 us; speedup vs baseline: 7.1632x; 1.2741x over previous
//
#include <hip/hip_runtime.h>
#include <math.h>

#define HI 128
#define WI 128
#define BB 2
#define PG 1024
#define NE (BB*PG)

#define OFF_ALPHA (BB*3*HI*WI)            /* 98304  */
#define OFF_ESTC  (OFF_ALPHA + BB*HI*WI)  /* 131072 */
#define OFF_ESTW  (OFF_ESTC + BB*PG*3)    /* 137216 */
#define OFF_RADII (OFF_ESTW + BB*PG)      /* 139264 */

// ws layout (float4 units):
//  preA[NE] (px,py,A,B)   preB[NE] (C,pmin,op,-)  preC[NE] (cR,cG,cB,-)
//  preD[NE] (px,py,ex,ey) srtA[NE] srtB[NE](..,idxbits) srtC[NE] cull[NE]
//  keys[NE] uint (sortable depth bits)

__global__ __launch_bounds__(256) void preprocess_kernel(
    const float* __restrict__ means, const float* __restrict__ sh,
    const float* __restrict__ opac, const float* __restrict__ scales,
    const float* __restrict__ rots, const float* __restrict__ vm,
    const float* __restrict__ pm, const float* __restrict__ campos,
    float4* __restrict__ preA, float4* __restrict__ preB,
    float4* __restrict__ preC, float4* __restrict__ preD,
    unsigned int* __restrict__ keys, float* __restrict__ radii_out,
    float4* __restrict__ est_zero)
{
  int gid = blockIdx.x * blockDim.x + threadIdx.x;
  if (gid >= NE) return;

  est_zero[gid] = make_float4(0.f, 0.f, 0.f, 0.f);   // zero est_color+est_weight

  float mx = means[gid*3+0], my = means[gid*3+1], mz = means[gid*3+2];

  float hom0 = pm[0]*mx + pm[1]*my + pm[2]*mz + pm[3];
  float hom1 = pm[4]*mx + pm[5]*my + pm[6]*mz + pm[7];
  float hom3 = pm[12]*mx + pm[13]*my + pm[14]*mz + pm[15];
  float p_w  = 1.0f / (hom3 + 1e-7f);
  float pp0 = hom0 * p_w, pp1 = hom1 * p_w;

  float pv0   = vm[0]*mx + vm[1]*my + vm[2]*mz  + vm[3];
  float pv1   = vm[4]*mx + vm[5]*my + vm[6]*mz  + vm[7];
  float depth = vm[8]*mx + vm[9]*my + vm[10]*mz + vm[11];

  float qr = rots[gid*4+0], qx = rots[gid*4+1], qy = rots[gid*4+2], qz = rots[gid*4+3];
  float qn = sqrtf(qr*qr + qx*qx + qy*qy + qz*qz);
  qr /= qn; qx /= qn; qy /= qn; qz /= qn;
  float R00 = 1.0f-2.0f*(qy*qy+qz*qz), R01 = 2.0f*(qx*qy-qr*qz), R02 = 2.0f*(qx*qz+qr*qy);
  float R10 = 2.0f*(qx*qy+qr*qz), R11 = 1.0f-2.0f*(qx*qx+qz*qz), R12 = 2.0f*(qy*qz-qr*qx);
  float R20 = 2.0f*(qx*qz-qr*qy), R21 = 2.0f*(qy*qz+qr*qx), R22 = 1.0f-2.0f*(qx*qx+qy*qy);

  float s0 = scales[gid*3+0], s1 = scales[gid*3+1], s2 = scales[gid*3+2];
  float M00=R00*s0, M01=R01*s1, M02=R02*s2;
  float M10=R10*s0, M11=R11*s1, M12=R12*s2;
  float M20=R20*s0, M21=R21*s1, M22=R22*s2;
  float S00 = M00*M00+M01*M01+M02*M02;
  float S01 = M00*M10+M01*M11+M02*M12;
  float S02 = M00*M20+M01*M21+M02*M22;
  float S11 = M10*M10+M11*M11+M12*M12;
  float S12 = M10*M20+M11*M21+M12*M22;
  float S22 = M20*M20+M21*M21+M22*M22;

  const float fx = 128.0f, fyc = 128.0f;
  float tz = depth;
  float txc = fminf(fmaxf(pv0/tz, -0.65f), 0.65f) * tz;
  float tyc = fminf(fmaxf(pv1/tz, -0.65f), 0.65f) * tz;
  float J00 = fx/tz,  J02 = -fx*txc/(tz*tz);
  float J11 = fyc/tz, J12 = -fyc*tyc/(tz*tz);

  float T00 = J00*vm[0] + J02*vm[8];
  float T01 = J00*vm[1] + J02*vm[9];
  float T02 = J00*vm[2] + J02*vm[10];
  float T10 = J11*vm[4] + J12*vm[8];
  float T11 = J11*vm[5] + J12*vm[9];
  float T12 = J11*vm[6] + J12*vm[10];

  float TS00 = T00*S00 + T01*S01 + T02*S02;
  float TS01 = T00*S01 + T01*S11 + T02*S12;
  float TS02 = T00*S02 + T01*S12 + T02*S22;
  float TS10 = T10*S00 + T11*S01 + T12*S02;
  float TS11 = T10*S01 + T11*S11 + T12*S12;
  float TS12 = T10*S02 + T11*S12 + T12*S22;

  float c00 = TS00*T00 + TS01*T01 + TS02*T02 + 0.3f;
  float c01 = TS00*T10 + TS01*T11 + TS02*T12;
  float c11 = TS10*T10 + TS11*T11 + TS12*T12 + 0.3f;

  float det = c00*c11 - c01*c01;
  bool valid = (depth > 0.2f) && (det > 1e-12f);
  float inv_det = 1.0f / (det > 1e-12f ? det : 1.0f);
  float A  =  c11 * inv_det;
  float Bc = -c01 * inv_det;
  float Cc =  c00 * inv_det;
  float mid = 0.5f * (c00 + c11);
  float lam = mid + sqrtf(fmaxf(mid*mid - det, 0.1f));
  float radii = valid ? ceilf(3.0f * sqrtf(lam)) : 0.0f;

  float px = ((pp0 + 1.0f)*WI - 1.0f)*0.5f;
  float py = ((pp1 + 1.0f)*HI - 1.0f)*0.5f;

  // SH degree 3
  float dxr = mx - campos[0], dyr = my - campos[1], dzr = mz - campos[2];
  float dn = sqrtf(dxr*dxr + dyr*dyr + dzr*dzr);
  float x = dxr/dn, y = dyr/dn, z = dzr/dn;
  float xx=x*x, yy=y*y, zz=z*z, xy=x*y, yz=y*z, xz=x*z;
  const float* S = sh + gid*48;
  float col[3];
  #pragma unroll
  for (int c = 0; c < 3; ++c) {
    float r = 0.28209479177387814f * S[0+c];
    r -= 0.4886025119029199f * y * S[3+c];
    r += 0.4886025119029199f * z * S[6+c];
    r -= 0.4886025119029199f * x * S[9+c];
    r += 1.0925484305920792f  * xy * S[12+c];
    r += -1.0925484305920792f * yz * S[15+c];
    r += 0.31539156525252005f * (2.0f*zz-xx-yy) * S[18+c];
    r += -1.0925484305920792f * xz * S[21+c];
    r += 0.5462742152960396f  * (xx-yy) * S[24+c];
    r += -0.5900435899266435f * y * (3.0f*xx-yy) * S[27+c];
    r += 2.890611442640554f   * xy * z * S[30+c];
    r += -0.4570457994644658f * y * (4.0f*zz-xx-yy) * S[33+c];
    r += 0.3731763325901154f  * z * (2.0f*zz-3.0f*xx-3.0f*yy) * S[36+c];
    r += -0.4570457994644658f * x * (4.0f*zz-xx-yy) * S[39+c];
    r += 1.445305721320277f   * z * (xx-yy) * S[42+c];
    r += -0.5900435899266435f * x * (xx-3.0f*yy) * S[45+c];
    col[c] = fmaxf(r + 0.5f, 0.0f);
  }

  float op = opac[gid];
  float tau = logf(255.0f * op);           // -pmin
  bool rok = valid && (tau > 0.0f);
  float ex = rok ? sqrtf(2.0f*tau*c00) + 0.02f : -1e9f;
  float ey = rok ? sqrtf(2.0f*tau*c11) + 0.02f : -1e9f;

  preA[gid] = make_float4(px, py, A, Bc);
  preB[gid] = make_float4(Cc, -tau, op, 0.0f);
  preC[gid] = make_float4(col[0], col[1], col[2], 0.0f);
  preD[gid] = make_float4(px, py, ex, ey);

  unsigned int u = __float_as_uint(depth);
  u = (u >> 31) ? ~u : (u | 0x80000000u);   // sortable: ascending float order
  keys[gid] = u;
  radii_out[gid] = radii;
}

// Stable rank sort: rank = #(key64_j < key64_i), key64 = (u<<10)|idx.
__global__ __launch_bounds__(256) void rank_pack_kernel(
    const float4* __restrict__ preA, const float4* __restrict__ preB,
    const float4* __restrict__ preC, const float4* __restrict__ preD,
    const unsigned int* __restrict__ keys,
    float4* __restrict__ srtA, float4* __restrict__ srtB,
    float4* __restrict__ srtC, float4* __restrict__ cull)
{
  int e = blockIdx.x * 256 + threadIdx.x;
  int b = e >> 10, i = e & (PG - 1);
  const unsigned int* kb = keys + (b << 10);
  unsigned long long ki = (((unsigned long long)kb[i]) << 10) | (unsigned)i;
  int rank = 0;
  const uint4* k4 = (const uint4*)kb;
  for (int j4 = 0; j4 < PG/4; ++j4) {
    uint4 kv = k4[j4];
    int j = j4 * 4;
    rank += ((((unsigned long long)kv.x) << 10) | (unsigned)(j+0)) < ki;
    rank += ((((unsigned long long)kv.y) << 10) | (unsigned)(j+1)) < ki;
    rank += ((((unsigned long long)kv.z) << 10) | (unsigned)(j+2)) < ki;
    rank += ((((unsigned long long)kv.w) << 10) | (unsigned)(j+3)) < ki;
  }
  int r = (b << 10) + rank;
  float4 qb = preB[e];
  qb.w = __int_as_float(i);      // original index
  srtA[r] = preA[e];
  srtB[r] = qb;
  srtC[r] = preC[e];
  cull[r] = preD[e];
}

__global__ __launch_bounds__(64) void render_kernel(
    const float4* __restrict__ srtA, const float4* __restrict__ srtB,
    const float4* __restrict__ srtC, const float4* __restrict__ cull,
    const float* __restrict__ target, const float* __restrict__ bg,
    float* __restrict__ out)
{
  const int b = blockIdx.z;
  const int t = threadIdx.x;
  const int x = blockIdx.x*8 + (t & 7);
  const int y = blockIdx.y*8 + (t >> 3);
  const float fxp = (float)x, fyp = (float)y;
  const float tx0 = (float)(blockIdx.x*8), ty0 = (float)(blockIdx.y*8);

  __shared__ int    sidx[PG];
  __shared__ float4 sqA[64], sqB[64], sqC[64];
  __shared__ float4 stgt[64];
  __shared__ float  wmat[64][65];          // padded: 2-way banks only

  // ---- per-tile survivor list (order-preserving) ----
  const float4* csrc = cull + (b << 10);
  int total = 0;
  #pragma unroll
  for (int c0 = 0; c0 < PG; c0 += 64) {
    float4 cv = csrc[c0 + t];
    bool ok = (cv.x + cv.z >= tx0) && (cv.x - cv.z <= tx0 + 7.0f)
           && (cv.y + cv.w >= ty0) && (cv.y - cv.w <= ty0 + 7.0f);
    unsigned long long m = __ballot(ok);
    if (ok) {
      int pos = total + __popcll(m & ((1ull << t) - 1ull));
      sidx[pos] = c0 + t;
    }
    total += __popcll(m);
  }

  const float t0 = target[((b*3+0)*HI + y)*WI + x];
  const float t1 = target[((b*3+1)*HI + y)*WI + x];
  const float t2 = target[((b*3+2)*HI + y)*WI + x];
  stgt[t] = make_float4(t0, t1, t2, 1.0f);
  __syncthreads();

  float* est_col = out + OFF_ESTC + b*PG*3;
  float* est_w   = out + OFF_ESTW + b*PG;

  float T = 1.0f, a0 = 0.0f, a1 = 0.0f, a2 = 0.0f;

  for (int c = 0; c < total; c += 64) {
    int count = min(64, total - c);
    if (t < count) {
      int g = (b << 10) + sidx[c + t];
      sqA[t] = srtA[g]; sqB[t] = srtB[g]; sqC[t] = srtC[g];
    }
    __syncthreads();

    for (int i = 0; i < count; ++i) {
      float4 q0 = sqA[i], q1 = sqB[i], q2 = sqC[i];
      float dx = q0.x - fxp, dy = q0.y - fyp;
      float power = -0.5f*(q0.z*dx*dx + q1.x*dy*dy) - q0.w*dx*dy;
      float alpha = fminf(0.99f, q1.z * __expf(power));
      bool keep = (power <= 0.0f) && (alpha >= (1.0f/255.0f));
      float w = keep ? alpha * T : 0.0f;
      a0 += w * q2.x; a1 += w * q2.y; a2 += w * q2.z;
      T -= w;
      wmat[i][t] = w;
    }
    __syncthreads();

    if (t < count) {
      float4 acc = make_float4(0.f, 0.f, 0.f, 0.f);
      #pragma unroll 8
      for (int p = 0; p < 64; ++p) {
        float w = wmat[t][p];
        float4 tg = stgt[p];
        acc.x += w * tg.x; acc.y += w * tg.y; acc.z += w * tg.z; acc.w += w;
      }
      int orig = __float_as_int(sqB[t].w);
      atomicAdd(&est_col[orig*3+0], acc.x);
      atomicAdd(&est_col[orig*3+1], acc.y);
      atomicAdd(&est_col[orig*3+2], acc.z);
      atomicAdd(&est_w[orig], acc.w);
    }
    __syncthreads();
  }

  out[((b*3+0)*HI + y)*WI + x] = a0 + T * bg[b*3+0];
  out[((b*3+1)*HI + y)*WI + x] = a1 + T * bg[b*3+1];
  out[((b*3+2)*HI + y)*WI + x] = a2 + T * bg[b*3+2];
  out[OFF_ALPHA + (b*HI + y)*WI + x] = 1.0f - T;
}

extern "C" void kernel_launch(void* const* d_in, const int* in_sizes, int n_in,
                              void* d_out, int out_size, void* d_ws, size_t ws_size,
                              hipStream_t stream) {
  const float* means  = (const float*)d_in[0];
  const float* sh     = (const float*)d_in[1];
  const float* opac   = (const float*)d_in[2];
  const float* scales = (const float*)d_in[3];
  const float* rots   = (const float*)d_in[4];
  const float* target = (const float*)d_in[5];
  const float* bg     = (const float*)d_in[6];
  const float* vm     = (const float*)d_in[7];
  const float* pm     = (const float*)d_in[8];
  const float* campos = (const float*)d_in[9];
  float* out = (float*)d_out;

  float4* preA = (float4*)d_ws;
  float4* preB = preA + NE;
  float4* preC = preB + NE;
  float4* preD = preC + NE;
  float4* srtA = preD + NE;
  float4* srtB = srtA + NE;
  float4* srtC = srtB + NE;
  float4* cul  = srtC + NE;
  unsigned int* keys = (unsigned int*)(cul + NE);

  preprocess_kernel<<<NE/256, 256, 0, stream>>>(
      means, sh, opac, scales, rots, vm, pm, campos,
      preA, preB, preC, preD, keys, out + OFF_RADII,
      (float4*)(out + OFF_ESTC));

  rank_pack_kernel<<<NE/256, 256, 0, stream>>>(
      preA, preB, preC, preD, keys, srtA, srtB, srtC, cul);

  dim3 grid(WI/8, HI/8, BB), block(64, 1);
  render_kernel<<<grid, block, 0, stream>>>(srtA, srtB, srtC, cul, target, bg, out);
}

// Round 4
// 23.548 us; speedup vs baseline: 13.9834x; 1.9521x over previous
//
#include <hip/hip_runtime.h>
#include <math.h>

#define HI 128
#define WI 128
#define BB 2
#define PG 1024
#define NE (BB*PG)

#define OFF_ALPHA (BB*3*HI*WI)            /* 98304  */
#define OFF_ESTC  (OFF_ALPHA + BB*HI*WI)  /* 131072 */
#define OFF_ESTW  (OFF_ESTC + BB*PG*3)    /* 137216 */
#define OFF_RADII (OFF_ESTW + BB*PG)      /* 139264 */

// ws layout (original-index order, no global sort):
//  preA[NE] (px,py,A,B)  preB[NE] (C,pmin,op,0)  preC[NE] (cR,cG,cB,0)
//  cull[NE] (px,py,ex,ey)  keys[NE] u32 sortable-depth

__global__ __launch_bounds__(256) void preprocess_kernel(
    const float* __restrict__ means, const float* __restrict__ sh,
    const float* __restrict__ opac, const float* __restrict__ scales,
    const float* __restrict__ rots, const float* __restrict__ vm,
    const float* __restrict__ pm, const float* __restrict__ campos,
    float4* __restrict__ preA, float4* __restrict__ preB,
    float4* __restrict__ preC, float4* __restrict__ cull,
    unsigned int* __restrict__ keys, float* __restrict__ radii_out,
    float4* __restrict__ est_zero)
{
  int gid = blockIdx.x * blockDim.x + threadIdx.x;
  if (gid >= NE) return;

  est_zero[gid] = make_float4(0.f, 0.f, 0.f, 0.f);   // zero est_color+est_weight

  float mx = means[gid*3+0], my = means[gid*3+1], mz = means[gid*3+2];

  float hom0 = pm[0]*mx + pm[1]*my + pm[2]*mz + pm[3];
  float hom1 = pm[4]*mx + pm[5]*my + pm[6]*mz + pm[7];
  float hom3 = pm[12]*mx + pm[13]*my + pm[14]*mz + pm[15];
  float p_w  = 1.0f / (hom3 + 1e-7f);
  float pp0 = hom0 * p_w, pp1 = hom1 * p_w;

  float pv0   = vm[0]*mx + vm[1]*my + vm[2]*mz  + vm[3];
  float pv1   = vm[4]*mx + vm[5]*my + vm[6]*mz  + vm[7];
  float depth = vm[8]*mx + vm[9]*my + vm[10]*mz + vm[11];

  float qr = rots[gid*4+0], qx = rots[gid*4+1], qy = rots[gid*4+2], qz = rots[gid*4+3];
  float qn = sqrtf(qr*qr + qx*qx + qy*qy + qz*qz);
  qr /= qn; qx /= qn; qy /= qn; qz /= qn;
  float R00 = 1.0f-2.0f*(qy*qy+qz*qz), R01 = 2.0f*(qx*qy-qr*qz), R02 = 2.0f*(qx*qz+qr*qy);
  float R10 = 2.0f*(qx*qy+qr*qz), R11 = 1.0f-2.0f*(qx*qx+qz*qz), R12 = 2.0f*(qy*qz-qr*qx);
  float R20 = 2.0f*(qx*qz-qr*qy), R21 = 2.0f*(qy*qz+qr*qx), R22 = 1.0f-2.0f*(qx*qx+qy*qy);

  float s0 = scales[gid*3+0], s1 = scales[gid*3+1], s2 = scales[gid*3+2];
  float M00=R00*s0, M01=R01*s1, M02=R02*s2;
  float M10=R10*s0, M11=R11*s1, M12=R12*s2;
  float M20=R20*s0, M21=R21*s1, M22=R22*s2;
  float S00 = M00*M00+M01*M01+M02*M02;
  float S01 = M00*M10+M01*M11+M02*M12;
  float S02 = M00*M20+M01*M21+M02*M22;
  float S11 = M10*M10+M11*M11+M12*M12;
  float S12 = M10*M20+M11*M21+M12*M22;
  float S22 = M20*M20+M21*M21+M22*M22;

  const float fx = 128.0f, fyc = 128.0f;
  float tz = depth;
  float txc = fminf(fmaxf(pv0/tz, -0.65f), 0.65f) * tz;
  float tyc = fminf(fmaxf(pv1/tz, -0.65f), 0.65f) * tz;
  float J00 = fx/tz,  J02 = -fx*txc/(tz*tz);
  float J11 = fyc/tz, J12 = -fyc*tyc/(tz*tz);

  float T00 = J00*vm[0] + J02*vm[8];
  float T01 = J00*vm[1] + J02*vm[9];
  float T02 = J00*vm[2] + J02*vm[10];
  float T10 = J11*vm[4] + J12*vm[8];
  float T11 = J11*vm[5] + J12*vm[9];
  float T12 = J11*vm[6] + J12*vm[10];

  float TS00 = T00*S00 + T01*S01 + T02*S02;
  float TS01 = T00*S01 + T01*S11 + T02*S12;
  float TS02 = T00*S02 + T01*S12 + T02*S22;
  float TS10 = T10*S00 + T11*S01 + T12*S02;
  float TS11 = T10*S01 + T11*S11 + T12*S12;
  float TS12 = T10*S02 + T11*S12 + T12*S22;

  float c00 = TS00*T00 + TS01*T01 + TS02*T02 + 0.3f;
  float c01 = TS00*T10 + TS01*T11 + TS02*T12;
  float c11 = TS10*T10 + TS11*T11 + TS12*T12 + 0.3f;

  float det = c00*c11 - c01*c01;
  bool valid = (depth > 0.2f) && (det > 1e-12f);
  float inv_det = 1.0f / (det > 1e-12f ? det : 1.0f);
  float A  =  c11 * inv_det;
  float Bc = -c01 * inv_det;
  float Cc =  c00 * inv_det;
  float mid = 0.5f * (c00 + c11);
  float lam = mid + sqrtf(fmaxf(mid*mid - det, 0.1f));
  float radii = valid ? ceilf(3.0f * sqrtf(lam)) : 0.0f;

  float px = ((pp0 + 1.0f)*WI - 1.0f)*0.5f;
  float py = ((pp1 + 1.0f)*HI - 1.0f)*0.5f;

  // SH degree 3
  float dxr = mx - campos[0], dyr = my - campos[1], dzr = mz - campos[2];
  float dn = sqrtf(dxr*dxr + dyr*dyr + dzr*dzr);
  float x = dxr/dn, y = dyr/dn, z = dzr/dn;
  float xx=x*x, yy=y*y, zz=z*z, xy=x*y, yz=y*z, xz=x*z;
  const float* S = sh + gid*48;
  float col[3];
  #pragma unroll
  for (int c = 0; c < 3; ++c) {
    float r = 0.28209479177387814f * S[0+c];
    r -= 0.4886025119029199f * y * S[3+c];
    r += 0.4886025119029199f * z * S[6+c];
    r -= 0.4886025119029199f * x * S[9+c];
    r += 1.0925484305920792f  * xy * S[12+c];
    r += -1.0925484305920792f * yz * S[15+c];
    r += 0.31539156525252005f * (2.0f*zz-xx-yy) * S[18+c];
    r += -1.0925484305920792f * xz * S[21+c];
    r += 0.5462742152960396f  * (xx-yy) * S[24+c];
    r += -0.5900435899266435f * y * (3.0f*xx-yy) * S[27+c];
    r += 2.890611442640554f   * xy * z * S[30+c];
    r += -0.4570457994644658f * y * (4.0f*zz-xx-yy) * S[33+c];
    r += 0.3731763325901154f  * z * (2.0f*zz-3.0f*xx-3.0f*yy) * S[36+c];
    r += -0.4570457994644658f * x * (4.0f*zz-xx-yy) * S[39+c];
    r += 1.445305721320277f   * z * (xx-yy) * S[42+c];
    r += -0.5900435899266435f * x * (xx-3.0f*yy) * S[45+c];
    col[c] = fmaxf(r + 0.5f, 0.0f);
  }

  float op = opac[gid];
  float tau = logf(255.0f * op);           // -pmin
  bool rok = valid && (tau > 0.0f);
  float ex = rok ? sqrtf(2.0f*tau*c00) + 0.02f : -1e9f;
  float ey = rok ? sqrtf(2.0f*tau*c11) + 0.02f : -1e9f;

  preA[gid] = make_float4(px, py, A, Bc);
  preB[gid] = make_float4(Cc, -tau, op, 0.0f);
  preC[gid] = make_float4(col[0], col[1], col[2], 0.0f);
  cull[gid] = make_float4(px, py, ex, ey);

  unsigned int u = __float_as_uint(depth);
  keys[gid] = (u >> 31) ? ~u : (u | 0x80000000u);   // ascending-sortable
  radii_out[gid] = radii;
}

__global__ __launch_bounds__(64) void render_kernel(
    const float4* __restrict__ preA, const float4* __restrict__ preB,
    const float4* __restrict__ preC, const float4* __restrict__ cull,
    const unsigned int* __restrict__ keys,
    const float* __restrict__ target, const float* __restrict__ bg,
    float* __restrict__ out)
{
  const int b = blockIdx.z;
  const int t = threadIdx.x;
  const int x = blockIdx.x*8 + (t & 7);
  const int y = blockIdx.y*8 + (t >> 3);
  const float fxp = (float)x, fyp = (float)y;
  const float tx0 = (float)(blockIdx.x*8), ty0 = (float)(blockIdx.y*8);

  __shared__ unsigned long long skey[PG];   // (depthkey<<10)|idx, survivors
  __shared__ float4 sqA[64], sqB[64], sqC[64];
  __shared__ float4 stgt[64];
  __shared__ float  wmat[64][65];           // padded: conflict-free both axes

  const float4* csrc = cull + (b << 10);
  const unsigned int* kb = keys + (b << 10);

  // ---- per-tile survivor collection (any order; sort fixes it) ----
  int total = 0;
  #pragma unroll
  for (int c0 = 0; c0 < PG; c0 += 64) {
    float4 cv = csrc[c0 + t];
    unsigned int kk = kb[c0 + t];
    bool ok = (cv.x + cv.z >= tx0) && (cv.x - cv.z <= tx0 + 7.0f)
           && (cv.y + cv.w >= ty0) && (cv.y - cv.w <= ty0 + 7.0f);
    unsigned long long m = __ballot(ok);
    if (ok) {
      int pos = total + __popcll(m & ((1ull << t) - 1ull));
      skey[pos] = (((unsigned long long)kk) << 10) | (unsigned)(c0 + t);
    }
    total += __popcll(m);
  }
  __syncthreads();

  // ---- sort survivors by (depth, idx): exact stable-argsort order ----
  if (total > 1) {
    if (total <= 64) {
      unsigned long long v = (t < total) ? skey[t] : ~0ull;
      #pragma unroll
      for (int k = 2; k <= 64; k <<= 1) {
        bool dirAsc = ((t & k) == 0);
        #pragma unroll
        for (int j = k >> 1; j > 0; j >>= 1) {
          unsigned long long o = __shfl_xor(v, j, 64);
          bool takeMin = (((t & j) == 0) == dirAsc);
          bool less = v < o;
          v = (takeMin == less) ? v : o;
        }
      }
      if (t < total) skey[t] = v;
    } else {
      int M = 64; while (M < total) M <<= 1;
      for (int s = total + t; s < M; s += 64) skey[s] = ~0ull;
      __syncthreads();
      for (int k = 2; k <= M; k <<= 1) {
        for (int j = k >> 1; j > 0; j >>= 1) {
          for (int base = t; base < M; base += 64) {
            int ixj = base ^ j;
            if (ixj > base) {
              unsigned long long a = skey[base], bq = skey[ixj];
              bool up = ((base & k) == 0);
              if ((a > bq) == up) { skey[base] = bq; skey[ixj] = a; }
            }
          }
          __syncthreads();
        }
      }
    }
  }

  const float t0 = target[((b*3+0)*HI + y)*WI + x];
  const float t1 = target[((b*3+1)*HI + y)*WI + x];
  const float t2 = target[((b*3+2)*HI + y)*WI + x];
  stgt[t] = make_float4(t0, t1, t2, 1.0f);
  __syncthreads();

  float* est_col = out + OFF_ESTC + b*PG*3;
  float* est_w   = out + OFF_ESTW + b*PG;

  float T = 1.0f, a0 = 0.0f, a1 = 0.0f, a2 = 0.0f;

  for (int c = 0; c < total; c += 64) {
    int count = min(64, total - c);
    if (t < count) {
      int g = (int)(skey[c + t] & 1023u);
      int e = (b << 10) + g;
      float4 qb = preB[e];
      qb.w = __int_as_float(g);
      sqA[t] = preA[e]; sqB[t] = qb; sqC[t] = preC[e];
    }
    __syncthreads();

    for (int i = 0; i < count; ++i) {
      float4 q0 = sqA[i], q1 = sqB[i], q2 = sqC[i];
      float dx = q0.x - fxp, dy = q0.y - fyp;
      float power = -0.5f*(q0.z*dx*dx + q1.x*dy*dy) - q0.w*dx*dy;
      float alpha = fminf(0.99f, q1.z * __expf(power));
      bool keep = (power <= 0.0f) && (alpha >= (1.0f/255.0f));
      float w = keep ? alpha * T : 0.0f;
      a0 += w * q2.x; a1 += w * q2.y; a2 += w * q2.z;
      T -= w;
      wmat[i][t] = w;
    }
    __syncthreads();

    if (t < count) {
      float4 acc = make_float4(0.f, 0.f, 0.f, 0.f);
      #pragma unroll 8
      for (int p = 0; p < 64; ++p) {
        float w = wmat[t][p];
        float4 tg = stgt[p];
        acc.x += w * tg.x; acc.y += w * tg.y; acc.z += w * tg.z; acc.w += w;
      }
      int orig = __float_as_int(sqB[t].w);
      atomicAdd(&est_col[orig*3+0], acc.x);
      atomicAdd(&est_col[orig*3+1], acc.y);
      atomicAdd(&est_col[orig*3+2], acc.z);
      atomicAdd(&est_w[orig], acc.w);
    }
    __syncthreads();
  }

  out[((b*3+0)*HI + y)*WI + x] = a0 + T * bg[b*3+0];
  out[((b*3+1)*HI + y)*WI + x] = a1 + T * bg[b*3+1];
  out[((b*3+2)*HI + y)*WI + x] = a2 + T * bg[b*3+2];
  out[OFF_ALPHA + (b*HI + y)*WI + x] = 1.0f - T;
}

extern "C" void kernel_launch(void* const* d_in, const int* in_sizes, int n_in,
                              void* d_out, int out_size, void* d_ws, size_t ws_size,
                              hipStream_t stream) {
  const float* means  = (const float*)d_in[0];
  const float* sh     = (const float*)d_in[1];
  const float* opac   = (const float*)d_in[2];
  const float* scales = (const float*)d_in[3];
  const float* rots   = (const float*)d_in[4];
  const float* target = (const float*)d_in[5];
  const float* bg     = (const float*)d_in[6];
  const float* vm     = (const float*)d_in[7];
  const float* pm     = (const float*)d_in[8];
  const float* campos = (const float*)d_in[9];
  float* out = (float*)d_out;

  float4* preA = (float4*)d_ws;
  float4* preB = preA + NE;
  float4* preC = preB + NE;
  float4* cul  = preC + NE;
  unsigned int* keys = (unsigned int*)(cul + NE);

  preprocess_kernel<<<NE/256, 256, 0, stream>>>(
      means, sh, opac, scales, rots, vm, pm, campos,
      preA, preB, preC, cul, keys, out + OFF_RADII,
      (float4*)(out + OFF_ESTC));

  dim3 grid(WI/8, HI/8, BB), block(64, 1);
  render_kernel<<<grid, block, 0, stream>>>(
      preA, preB, preC, cul, keys, target, bg, out);
}